// Round 6
// baseline (78.755 us; speedup 1.0000x reference)
//
#include <hip/hip_runtime.h>

// BallQLoss: ball_query(pc, r=0.2, k=16) against itself + L1 grouping loss.
// pc: (4, 4096, 3) f32, mask: (4, 4096, 30) f32 -> scalar f32.
// R6: float4 LDS tile (ds_read_b128, 1 instr/chunk), parallel peel via
// mbcnt+ds_permute (rank-ordered push replaces serial bit-peel), 1024-thread
// blocks (32 waves/CU), finisher folded in via last-block-done on a ws
// counter (no separate launch, no same-address float atomics).

#define BQ_B 4
#define BQ_N 4096
#define BQ_C 30
#define BQ_K 16
#define BQ_R2 0.04f
#define WAVES_PER_BLOCK 16
#define BLOCK_T (WAVES_PER_BLOCK * 64)      // 1024
#define BLOCKS_PER_BATCH 128
#define GRID (BQ_B * BLOCKS_PER_BATCH)      // 512 blocks = 2/CU, one round
#define QPB (BQ_N / BLOCKS_PER_BATCH)       // 32 queries/block, 2/wave

__global__ __launch_bounds__(BLOCK_T) void ballq_kernel(
    const float* __restrict__ pc,        // (B, N, 3)
    const float* __restrict__ mask,      // (B, N, C)
    float* __restrict__ partial,         // (GRID,) in d_ws
    unsigned int* __restrict__ counter,  // 1 uint in d_ws, zeroed per launch
    float* __restrict__ out)             // scalar
{
    __shared__ __align__(16) float4 spc4[BQ_N];   // 64 KB padded points
    __shared__ float wsum[WAVES_PER_BLOCK];
    __shared__ int is_last;

    const int tid  = threadIdx.x;
    const int lane = tid & 63;
    const int wave = tid >> 6;
    const int b   = blockIdx.x / BLOCKS_PER_BATCH;
    const int blk = blockIdx.x % BLOCKS_PER_BATCH;

    const float* pcb   = pc   + (size_t)b * BQ_N * 3;
    const float* maskb = mask + (size_t)b * BQ_N * BQ_C;

    // Stage pc into padded float4 LDS (4 points/thread).
    for (int p = tid; p < BQ_N; p += BLOCK_T)
        spc4[p] = make_float4(pcb[p * 3 + 0], pcb[p * 3 + 1], pcb[p * 3 + 2], 0.f);
    __syncthreads();

    float acc = 0.f;
    #pragma unroll
    for (int it = 0; it < QPB / WAVES_PER_BLOCK; ++it) {
        const int n = blk * QPB + wave + it * WAVES_PER_BLOCK;
        const float4 q = spc4[n];                       // wave-uniform broadcast
        const float qv = (lane < BQ_C) ? maskb[(size_t)n * BQ_C + lane] : 0.f;

        // ---- Phase 1: rank-parallel collection of first <=16 indices ----
        int found  = 0;
        int my_sel = 0;        // lane s (<16) ends holding slot s's index
        float4 cur = spc4[lane];

        for (int base = 0; base < BQ_N; base += 64) {
            const int nbase = (base + 64 < BQ_N) ? base + 64 : 0;
            const float4 nxt = spc4[nbase + lane];      // 1-deep prefetch

            const float dx = cur.x - q.x, dy = cur.y - q.y, dz = cur.z - q.z;
            const float d2 = dx * dx + dy * dy + dz * dz;
            const bool in = d2 < BQ_R2;
            const unsigned long long bal = __ballot(in);
            const int cnt  = __popcll(bal);
            // rank = # set bits strictly below my lane (index order in chunk)
            const int rank = __builtin_amdgcn_mbcnt_hi((unsigned)(bal >> 32),
                              __builtin_amdgcn_mbcnt_lo((unsigned)bal, 0));
            const int slot = found + rank;
            // In-ball lanes with slot<16 push their index to dest lane=slot;
            // everyone else routes to discard lanes [16,32) (no collisions
            // with real slots; discard collisions are harmless).
            const int dest = (in && slot < BQ_K) ? slot : (BQ_K + (lane & 15));
            const int tmp  = __builtin_amdgcn_ds_permute(dest << 2, base + lane);
            const int cap  = min(found + cnt, BQ_K);
            if (lane >= found && lane < cap) my_sel = tmp;
            found += cnt;
            if (found >= BQ_K) break;
            cur = nxt;
        }
        const int first = __shfl(my_sel, 0, 64);        // self => found >= 1
        if (lane < BQ_K && lane >= found) my_sel = first;  // reference padding

        // ---- Phase 2: 16 independent coalesced row loads ----
        float vals[BQ_K];
        #pragma unroll
        for (int s = 0; s < BQ_K; ++s) {
            const int nb = __shfl(my_sel, s, 64);       // v_readlane -> SGPR base
            vals[s] = (lane < BQ_C) ? maskb[(size_t)nb * BQ_C + lane] : 0.f;
        }
        float lsum = 0.f;
        #pragma unroll
        for (int s = 0; s < BQ_K; ++s) lsum += fabsf(qv - vals[s]);
        acc += lsum;
    }

    // Block reduction.
    for (int off = 32; off > 0; off >>= 1) acc += __shfl_xor(acc, off, 64);
    if (lane == 0) wsum[wave] = acc;
    __syncthreads();
    if (tid == 0) {
        float s = 0.f;
        #pragma unroll
        for (int w = 0; w < WAVES_PER_BLOCK; ++w) s += wsum[w];
        partial[blockIdx.x] = s;
        __threadfence();                      // release partials (device scope)
        const unsigned int old = atomicAdd(counter, 1u);
        is_last = (old == GRID - 1) ? 1 : 0;
    }
    __syncthreads();
    if (is_last && wave == 0) {               // last block folds the finisher
        __threadfence();                      // acquire others' partials
        const volatile float* vp = partial;
        float s = 0.f;
        for (int i = lane; i < GRID; i += 64) s += vp[i];
        for (int off = 32; off > 0; off >>= 1) s += __shfl_xor(s, off, 64);
        if (lane == 0)
            out[0] = s * (1.0f / ((float)BQ_B * BQ_N * BQ_K));
    }
}

extern "C" void kernel_launch(void* const* d_in, const int* in_sizes, int n_in,
                              void* d_out, int out_size, void* d_ws, size_t ws_size,
                              hipStream_t stream) {
    const float* pc   = (const float*)d_in[0];  // (4, 4096, 3)
    const float* mask = (const float*)d_in[1];  // (4, 4096, 30)
    float* out        = (float*)d_out;
    float* partial    = (float*)d_ws;                       // GRID floats
    unsigned int* cnt = (unsigned int*)((char*)d_ws + GRID * sizeof(float));

    // ws is re-poisoned 0xAA before every replay — zero the done-counter.
    hipMemsetAsync(cnt, 0, sizeof(unsigned int), stream);

    ballq_kernel<<<GRID, BLOCK_T, 0, stream>>>(pc, mask, partial, cnt, out);
}